// Round 8
// baseline (298.486 us; speedup 1.0000x reference)
//
#include <hip/hip_runtime.h>

// out[b,o] = sum_e ( relu(relu(x[b,e,:]@W1[e]+b1[e])@W2[e]+b2[e]) @ W3[e] + b3[e] )
// E=16, DIN=128, H=512, DOUT=64, B=8192.  94.5 GFLOP.
//
// R14 = R13 + weight-latency attack (single theory, two changes):
//  (1) NON-TEMPORAL x loads: x (64MB fp32) has ZERO line reuse (each (row,e)
//      read once by one block) yet streams through the 4MB XCD-L2s, evicting
//      the pinned W1/W2/W3 lines -> in-loop W2 frag loads bounce to L3
//      (~600-900cy) past the 2-kt (~620cy) lookahead. nt keeps x out of L2.
//  (2) L2-loop bfr 3->4 slots (lookahead-3 ~930cy, &3 indexing); W2 prologue
//      preloads s=0..2.  VGPR +16.
// R13 kept verbatim otherwise: sH double-buffer (sHA/sHB, 144KB, 2 barriers/
//   expert), EG=4 (atomics /4), no cross-expert W1 prefetch, rotating b3f[8],
//   X(e+1) 16-reg prefetch, swapped-operand epilogue, bias-in-acc, XCD expert
//   pinning, launch_bounds(512,2), folded memset, no setprio.

#define NE   16
#define NDIN 128
#define NH   512
#define NDO  64
#define NB   8192
#define EG   4

using bf16x8 = __attribute__((ext_vector_type(8))) __bf16;
using bf16x4 = __attribute__((ext_vector_type(4))) __bf16;
using f32x4  = __attribute__((ext_vector_type(4))) float;

__device__ __forceinline__ unsigned short f2bf(float f) {
    union { float f; unsigned u; } v; v.f = f;
    unsigned r = v.u + 0x7FFFu + ((v.u >> 16) & 1u);   // RNE
    return (unsigned short)(r >> 16);
}

// compiler-fusable bf16 conversion (emits v_cvt_pk_bf16_f32 pairs)
__device__ __forceinline__ bf16x8 cvt8(float4 a, float4 b) {
    bf16x8 r;
    r[0] = (__bf16)a.x; r[1] = (__bf16)a.y; r[2] = (__bf16)a.z; r[3] = (__bf16)a.w;
    r[4] = (__bf16)b.x; r[5] = (__bf16)b.y; r[6] = (__bf16)b.z; r[7] = (__bf16)b.w;
    return r;
}

// non-temporal float4 load (keeps zero-reuse x stream out of L2)
__device__ __forceinline__ float4 ntl4(const float* p) {
    float4 r;
    r.x = __builtin_nontemporal_load(p + 0);
    r.y = __builtin_nontemporal_load(p + 1);
    r.z = __builtin_nontemporal_load(p + 2);
    r.w = __builtin_nontemporal_load(p + 3);
    return r;
}

// Swizzled index (ushort units): 16B granules XOR'd by row&15 (0 conflicts measured).
__device__ __forceinline__ int shidx(int m, int n) {          // H tile, stride 512
    return m * NH + (((n >> 3) ^ (m & 15)) << 3) + (n & 7);
}
__device__ __forceinline__ int shx(int m, int n) {            // X tile, stride 128
    return m * NDIN + ((((n >> 3) ^ (m & 15)) & 15) << 3) + (n & 7);
}

// ---------------- merged prep: fp32 [e][R][C] -> bf16 [e][C][R]  (+ out zeroing) ----------------
__global__ __launch_bounds__(256) void prep_weights(
    const float* __restrict__ W1, const float* __restrict__ W2, const float* __restrict__ W3,
    unsigned short* __restrict__ W1t, unsigned short* __restrict__ W2t, unsigned short* __restrict__ W3t,
    float* __restrict__ out)
{
    __shared__ float tile[64][65];
    const int t = blockIdx.x, e = blockIdx.y;
    // fold the output memset into this dispatch: 64 blocks x 32KB = 2MB
    if (e == 0 && t < 64) {
        float4* oz = (float4*)(out + (size_t)t * 8192);
        const float4 z = {0.f, 0.f, 0.f, 0.f};
#pragma unroll
        for (int i = 0; i < 8; ++i) oz[i * 256 + threadIdx.x] = z;
    }
    const float* src; unsigned short* dst; int R, C, tr, tc;
    if (t < 16)      { src = W1; dst = W1t; R = NDIN; C = NH;  tr = t >> 3;        tc = t & 7;  }
    else if (t < 80) { src = W2; dst = W2t; R = NH;   C = NH;  tr = (t - 16) >> 3; tc = (t - 16) & 7; }
    else             { src = W3; dst = W3t; R = NH;   C = NDO; tr = t - 80;        tc = 0;      }
    const int r0 = tr * 64, c0 = tc * 64;
    const float* s = src + (size_t)e * R * C;
    unsigned short* d = dst + (size_t)e * R * C;
    const int tt = threadIdx.x;
#pragma unroll
    for (int i = 0; i < 4; ++i) {
        int f = i * 256 + tt;
        int r = f >> 4, c4 = (f & 15) * 4;
        const float4 v = *(const float4*)(s + (size_t)(r0 + r) * C + c0 + c4);
        tile[r][c4 + 0] = v.x; tile[r][c4 + 1] = v.y;
        tile[r][c4 + 2] = v.z; tile[r][c4 + 3] = v.w;
    }
    __syncthreads();
#pragma unroll
    for (int i = 0; i < 4; ++i) {
        int f = i * 256 + tt;
        int cc = f >> 4, rb = (f & 15) * 4;
        ushort4 o;
        o.x = f2bf(tile[rb + 0][cc]);
        o.y = f2bf(tile[rb + 1][cc]);
        o.z = f2bf(tile[rb + 2][cc]);
        o.w = f2bf(tile[rb + 3][cc]);
        *(ushort4*)(d + (size_t)(c0 + cc) * R + r0 + rb) = o;
    }
}

// ---------------- fused 3-layer expert MLP: 4 experts x 64 rows per WG ----------------
__global__ __launch_bounds__(512, 2) void moe_fused(
    const float* __restrict__ x,            // [B][E][DIN]
    const float* __restrict__ b1,           // [E][H]
    const float* __restrict__ b2,           // [E][H]
    const float* __restrict__ b3,           // [E][DOUT]
    const unsigned short* __restrict__ W1t, // [E][H][DIN]  bf16
    const unsigned short* __restrict__ W2t, // [E][H][H]    bf16
    const unsigned short* __restrict__ W3t, // [E][DOUT][H] bf16
    float* __restrict__ out)                // [B][DOUT]  (pre-zeroed by prep)
{
    __shared__ unsigned short sMem[64 * NDIN + 2 * 64 * NH];  // 16KB X + 2x64KB H = 144KB
    unsigned short* sX  = sMem;
    unsigned short* sHA = sMem + 64 * NDIN;            // L1 output (read by L2)
    unsigned short* sHB = sHA + 64 * NH;               // L2 output (read by L3)

    const int tid  = threadIdx.x;
    const int wave = tid >> 6;
    const int lane = tid & 63;
    const int q    = lane >> 4;
    const int l16  = lane & 15;
    const int hi2  = l16 >> 2;
    const int lo2  = l16 & 3;
    const int qe   = (q ^ lo2) * 8;       // swizzled in-granule element offset

    // grid 512: xcd = lin&7; e-group = xcd>>1 (4 experts pinned per XCD pair);
    // row-tile = ((lin>>3)<<1)|(xcd&1) in 0..127.
    const int lin = blockIdx.x;
    const int xcd = lin & 7;
    const int eg  = xcd >> 1;
    const int rt  = ((lin >> 3) << 1) | (xcd & 1);
    const int b0  = rt << 6;
    const int nb  = wave * 64;

    // per-wave LDS A-frag base offsets (elements);  read addr = base + ((kt^hi2)<<5)
    int aH[4], aX[4];
#pragma unroll
    for (int m = 0; m < 4; ++m) {
        aH[m] = (m * 16 + l16) * NH   + qe;
        aX[m] = (m * 16 + l16) * NDIN + qe;
    }
    const int r0 = tid >> 4, c8 = (tid & 15) * 8;   // x staging coords

    // L3 wave mapping (constant across experts)
    const int n3 = wave & 3, mp = wave >> 2;
    int a3[2];
#pragma unroll
    for (int i = 0; i < 2; ++i) a3[i] = ((2 * mp + i) * 16 + l16) * NH + qe;

    bf16x8 bfr[4][4], afr[3][4];

    f32x4 oacc[2];
    oacc[0] = {0.f, 0.f, 0.f, 0.f}; oacc[1] = {0.f, 0.f, 0.f, 0.f};
    float bacc = 0.f;

    // ---- prologue: stage sX(e0) (non-temporal x reads) ----
    {
        const int e0 = eg * EG;
        const float* p0 = x + ((size_t)(b0 + r0)      * NE + e0) * NDIN + c8;
        const float* p1 = x + ((size_t)(b0 + 32 + r0) * NE + e0) * NDIN + c8;
        float4 u0 = ntl4(p0), u1 = ntl4(p0 + 4);
        float4 u2 = ntl4(p1), u3 = ntl4(p1 + 4);
        *(bf16x8*)&sX[shx(r0, c8)]      = cvt8(u0, u1);
        *(bf16x8*)&sX[shx(32 + r0, c8)] = cvt8(u2, u3);
    }
    __syncthreads();   // BAR-0: sX(e0) visible

#pragma unroll 1
    for (int ei = 0; ei < EG; ++ei) {
        const int e = eg * EG + ei;

        // W1 frags + b1 at iter top (L2-resident, amortized over 3 GEMMs)
        const unsigned short* wb1[4];
#pragma unroll
        for (int n = 0; n < 4; ++n)
            wb1[n] = W1t + (size_t)e * NH * NDIN + (size_t)(nb + n * 16 + l16) * NDIN + q * 8;
#pragma unroll
        for (int s = 0; s < 2; ++s)
#pragma unroll
            for (int n = 0; n < 4; ++n)
                bfr[s][n] = *(const bf16x8*)(wb1[n] + s * 32);
        float4 b1q[4];
#pragma unroll
        for (int n = 0; n < 4; ++n)
            b1q[n] = *(const float4*)(b1 + e * NH + nb + n * 16 + q * 4);

        // ---------------- layer 1: acc = X @ W1 + b1, 4 kt ----------------
        f32x4 acc[4][4];
#pragma unroll
        for (int n = 0; n < 4; ++n) {
            const f32x4 bi = {b1q[n].x, b1q[n].y, b1q[n].z, b1q[n].w};
#pragma unroll
            for (int m = 0; m < 4; ++m) acc[m][n] = bi;
        }
#pragma unroll
        for (int s = 0; s < 2; ++s)
#pragma unroll
            for (int m = 0; m < 4; ++m)
                afr[s][m] = *(const bf16x8*)&sX[aX[m] + (((s ^ hi2) & 3) << 5)];

#pragma unroll
        for (int kt = 0; kt < 4; ++kt) {
            const int cur = kt & 3, pre = (kt + 2) & 3;
            if (kt < 2) {
#pragma unroll
                for (int n = 0; n < 4; ++n)
                    bfr[pre][n] = *(const bf16x8*)(wb1[n] + (kt + 2) * 32);
#pragma unroll
                for (int m = 0; m < 4; ++m)
                    afr[(kt + 2) % 3][m] = *(const bf16x8*)&sX[aX[m] + ((((kt + 2) ^ hi2) & 3) << 5)];
            }
#pragma unroll
            for (int m = 0; m < 4; ++m)
#pragma unroll
                for (int n = 0; n < 4; ++n)
                    acc[m][n] = __builtin_amdgcn_mfma_f32_16x16x32_bf16(
                        bfr[cur][n], afr[kt % 3][m], acc[m][n], 0, 0, 0);
        }

        // W2 prologue (slots 0..2, lookahead-3) + b2 in flight over H1 epilogue + barrier
        const unsigned short* wb2[4];
#pragma unroll
        for (int n = 0; n < 4; ++n)
            wb2[n] = W2t + (size_t)e * NH * NH + (size_t)(nb + n * 16 + l16) * NH + q * 8;
#pragma unroll
        for (int s = 0; s < 3; ++s)
#pragma unroll
            for (int n = 0; n < 4; ++n)
                bfr[s][n] = *(const bf16x8*)(wb2[n] + s * 32);
        float4 b2q[4];
#pragma unroll
        for (int n = 0; n < 4; ++n)
            b2q[n] = *(const float4*)(b2 + e * NH + nb + n * 16 + q * 4);

        // H1 epilogue -> sHA (WAR-safe: L2(e-1) readers ended before BAR-2(e-1))
#pragma unroll
        for (int n = 0; n < 4; ++n) {
            const int c0 = nb + n * 16 + q * 4;
#pragma unroll
            for (int m = 0; m < 4; ++m) {
                bf16x4 pk;
#pragma unroll
                for (int r = 0; r < 4; ++r) pk[r] = (__bf16)fmaxf(acc[m][n][r], 0.f);
                *(bf16x4*)&sHA[shidx(m * 16 + l16, c0)] = pk;
            }
        }
        __syncthreads();   // BAR-1: sHA visible (also orders L3(e-1) before H2epi below)

        // ---------------- layer 2: acc2 = H1 @ W2 (+b2), 16 kt, lookahead-3 ----------------
        f32x4 acc2[4][4];
#pragma unroll
        for (int n = 0; n < 4; ++n) {
            const f32x4 bi = {b2q[n].x, b2q[n].y, b2q[n].z, b2q[n].w};
#pragma unroll
            for (int m = 0; m < 4; ++m) acc2[m][n] = bi;
        }
#pragma unroll
        for (int s = 0; s < 2; ++s)
#pragma unroll
            for (int m = 0; m < 4; ++m)
                afr[s][m] = *(const bf16x8*)&sHA[aH[m] + (((s ^ hi2)) << 5)];

#pragma unroll
        for (int kt = 0; kt < 16; ++kt) {
            const int cur = kt & 3;
            if (kt < 13) {
                const int pre = (kt + 3) & 3;
#pragma unroll
                for (int n = 0; n < 4; ++n)
                    bfr[pre][n] = *(const bf16x8*)(wb2[n] + (kt + 3) * 32);
            }
            if (kt < 14)
#pragma unroll
                for (int m = 0; m < 4; ++m)
                    afr[(kt + 2) % 3][m] = *(const bf16x8*)&sHA[aH[m] + ((((kt + 2) ^ hi2)) << 5)];
#pragma unroll
            for (int m = 0; m < 4; ++m)
#pragma unroll
                for (int n = 0; n < 4; ++n)
                    acc2[m][n] = __builtin_amdgcn_mfma_f32_16x16x32_bf16(
                        bfr[cur][n], afr[kt % 3][m], acc2[m][n], 0, 0, 0);
        }

        // W3 first half + b3; X(e+1) -> regs (16 VGPR, held across one epilogue; nt loads)
        const unsigned short* wb3 = W3t + (size_t)e * NDO * NH + (size_t)(n3 * 16 + l16) * NH + q * 8;
        bf16x8 b3f[8];
#pragma unroll
        for (int j = 0; j < 8; ++j) b3f[j] = *(const bf16x8*)(wb3 + j * 32);
        const float b3v = b3[e * NDO + n3 * 16 + l16];

        float4 xu0, xu1, xu2, xu3;
        {
            const int en = eg * EG + ((ei + 1) & (EG - 1));   // wrap: ei=3 redundant, harmless
            const float* pn0 = x + ((size_t)(b0 + r0)      * NE + en) * NDIN + c8;
            const float* pn1 = x + ((size_t)(b0 + 32 + r0) * NE + en) * NDIN + c8;
            xu0 = ntl4(pn0); xu1 = ntl4(pn0 + 4);
            xu2 = ntl4(pn1); xu3 = ntl4(pn1 + 4);
        }

        // H2 epilogue -> sHB (WAR-safe: L3(e-1) readers ended before BAR-1(e))
#pragma unroll
        for (int n = 0; n < 4; ++n) {
            const int c0 = nb + n * 16 + q * 4;
#pragma unroll
            for (int m = 0; m < 4; ++m) {
                bf16x4 pk;
#pragma unroll
                for (int r = 0; r < 4; ++r) pk[r] = (__bf16)fmaxf(acc2[m][n][r], 0.f);
                *(bf16x4*)&sHB[shidx(m * 16 + l16, c0)] = pk;
            }
        }
        // stage sX(e+1) (WAR-safe: L1(e) readers ended before BAR-1(e))
        *(bf16x8*)&sX[shx(r0, c8)]      = cvt8(xu0, xu1);
        *(bf16x8*)&sX[shx(32 + r0, c8)] = cvt8(xu2, xu3);
        __syncthreads();   // BAR-2: sHB + sX(e+1) visible

        // ---------------- layer 3: oacc += H2 @ W3 (b3f[8] rotating; A lookahead-3) ----------------
        bf16x8 a3f[4][2];
#pragma unroll
        for (int s = 0; s < 3; ++s)
#pragma unroll
            for (int i = 0; i < 2; ++i)
                a3f[s][i] = *(const bf16x8*)&sHB[a3[i] + (((s ^ hi2)) << 5)];

#pragma unroll
        for (int kt = 0; kt < 16; ++kt) {
            const int cur = kt & 3;
            if (kt < 13) {
                const int pre = (kt + 3) & 3;
#pragma unroll
                for (int i = 0; i < 2; ++i)
                    a3f[pre][i] = *(const bf16x8*)&sHB[a3[i] + ((((kt + 3) ^ hi2)) << 5)];
            }
#pragma unroll
            for (int i = 0; i < 2; ++i)
                oacc[i] = __builtin_amdgcn_mfma_f32_16x16x32_bf16(
                    a3f[cur][i], b3f[kt & 7], oacc[i], 0, 0, 0);
            if (kt < 8)    // rotate: slot kt&7 dead after its MFMA; load frag kt+8
                b3f[kt & 7] = *(const bf16x8*)(wb3 + (kt + 8) * 32);
        }
        bacc += b3v;
    }

    // final: 4-expert-accumulated contribution -> global fp32 atomics (1 set per block)
#pragma unroll
    for (int i = 0; i < 2; ++i) {
        const int col = n3 * 16 + l16;
#pragma unroll
        for (int r = 0; r < 4; ++r) {
            const int row = b0 + (2 * mp + i) * 16 + q * 4 + r;
            unsafeAtomicAdd(out + (size_t)row * NDO + col, oacc[i][r] + bacc);
        }
    }
}

extern "C" void kernel_launch(void* const* d_in, const int* in_sizes, int n_in,
                              void* d_out, int out_size, void* d_ws, size_t ws_size,
                              hipStream_t stream) {
    const float* x  = (const float*)d_in[0];
    const float* W1 = (const float*)d_in[1];
    const float* b1 = (const float*)d_in[2];
    const float* W2 = (const float*)d_in[3];
    const float* b2 = (const float*)d_in[4];
    const float* W3 = (const float*)d_in[5];
    const float* b3 = (const float*)d_in[6];
    float* out = (float*)d_out;

    unsigned short* W1t = (unsigned short*)d_ws;            // [E][H][DIN]
    unsigned short* W2t = W1t + (size_t)NE * NH * NDIN;     // [E][H][H]
    unsigned short* W3t = W2t + (size_t)NE * NH * NH;       // [E][DOUT][H]

    prep_weights<<<dim3(88, NE), 256, 0, stream>>>(W1, W2, W3, W1t, W2t, W3t, out);
    moe_fused<<<dim3((NB / 64) * (NE / EG)), 512, 0, stream>>>(x, b1, b2, b3, W1t, W2t, W3t, out);
}

// Round 9
// 295.685 us; speedup vs baseline: 1.0095x; 1.0095x over previous
//
#include <hip/hip_runtime.h>

// out[b,o] = sum_e ( relu(relu(x[b,e,:]@W1[e]+b1[e])@W2[e]+b2[e]) @ W3[e] + b3[e] )
// E=16, DIN=128, H=512, DOUT=64, B=8192.  94.5 GFLOP.
//
// R15: genuine 16 waves/CU (4/SIMD) via total-register discipline.
// Diagnosis: gfx950 unified VGPR+AGPR file -> VGPR_Count(124) + acc AGPRs(~64)
// ~ 190/wave -> 2 waves/SIMD in every non-spill round; all pipes <25% busy =
// latency-bound. R11 tried 16 waves but kept 64 arch regs of L3 state -> spill.
// This round: ONE 1024-thread block (16 waves), per-wave budget ~115 total:
//   L1/L2: n-width 32 (acc 32 AGPR), afr SINGLE-buffered (16; 4-wave TLP covers
//   the ds_read latency - that's the point), bfr 2-slot (16).
//   L3: (2mp x 4n3 x 2kh) K-split; b3f[4] rotating (16) + a3f 2-slot (16);
//   oacc 8 AGPR; kh=1 skips bias (no double-count); atomics 2x (16.8MB, fine).
// Kept from R13/R14: dual-sH 2-barrier skeleton (WAR audit unchanged), EG=4,
//   swapped-operand b64 epilogue, bias-in-acc, XCD expert pinning, folded memset.

#define NE   16
#define NDIN 128
#define NH   512
#define NDO  64
#define NB   8192
#define EG   4

using bf16x8 = __attribute__((ext_vector_type(8))) __bf16;
using bf16x4 = __attribute__((ext_vector_type(4))) __bf16;
using f32x4  = __attribute__((ext_vector_type(4))) float;

__device__ __forceinline__ unsigned short f2bf(float f) {
    union { float f; unsigned u; } v; v.f = f;
    unsigned r = v.u + 0x7FFFu + ((v.u >> 16) & 1u);   // RNE
    return (unsigned short)(r >> 16);
}

// compiler-fusable bf16 conversion (emits v_cvt_pk_bf16_f32 pairs)
__device__ __forceinline__ bf16x8 cvt8(float4 a, float4 b) {
    bf16x8 r;
    r[0] = (__bf16)a.x; r[1] = (__bf16)a.y; r[2] = (__bf16)a.z; r[3] = (__bf16)a.w;
    r[4] = (__bf16)b.x; r[5] = (__bf16)b.y; r[6] = (__bf16)b.z; r[7] = (__bf16)b.w;
    return r;
}

// Swizzled index (ushort units): 16B granules XOR'd by row&15 (0 conflicts measured).
__device__ __forceinline__ int shidx(int m, int n) {          // H tile, stride 512
    return m * NH + (((n >> 3) ^ (m & 15)) << 3) + (n & 7);
}
__device__ __forceinline__ int shx(int m, int n) {            // X tile, stride 128
    return m * NDIN + ((((n >> 3) ^ (m & 15)) & 15) << 3) + (n & 7);
}

// ---------------- merged prep: fp32 [e][R][C] -> bf16 [e][C][R]  (+ out zeroing) ----------------
__global__ __launch_bounds__(256) void prep_weights(
    const float* __restrict__ W1, const float* __restrict__ W2, const float* __restrict__ W3,
    unsigned short* __restrict__ W1t, unsigned short* __restrict__ W2t, unsigned short* __restrict__ W3t,
    float* __restrict__ out)
{
    __shared__ float tile[64][65];
    const int t = blockIdx.x, e = blockIdx.y;
    // fold the output memset into this dispatch: 64 blocks x 32KB = 2MB
    if (e == 0 && t < 64) {
        float4* oz = (float4*)(out + (size_t)t * 8192);
        const float4 z = {0.f, 0.f, 0.f, 0.f};
#pragma unroll
        for (int i = 0; i < 8; ++i) oz[i * 256 + threadIdx.x] = z;
    }
    const float* src; unsigned short* dst; int R, C, tr, tc;
    if (t < 16)      { src = W1; dst = W1t; R = NDIN; C = NH;  tr = t >> 3;        tc = t & 7;  }
    else if (t < 80) { src = W2; dst = W2t; R = NH;   C = NH;  tr = (t - 16) >> 3; tc = (t - 16) & 7; }
    else             { src = W3; dst = W3t; R = NH;   C = NDO; tr = t - 80;        tc = 0;      }
    const int r0 = tr * 64, c0 = tc * 64;
    const float* s = src + (size_t)e * R * C;
    unsigned short* d = dst + (size_t)e * R * C;
    const int tt = threadIdx.x;
#pragma unroll
    for (int i = 0; i < 4; ++i) {
        int f = i * 256 + tt;
        int r = f >> 4, c4 = (f & 15) * 4;
        const float4 v = *(const float4*)(s + (size_t)(r0 + r) * C + c0 + c4);
        tile[r][c4 + 0] = v.x; tile[r][c4 + 1] = v.y;
        tile[r][c4 + 2] = v.z; tile[r][c4 + 3] = v.w;
    }
    __syncthreads();
#pragma unroll
    for (int i = 0; i < 4; ++i) {
        int f = i * 256 + tt;
        int cc = f >> 4, rb = (f & 15) * 4;
        ushort4 o;
        o.x = f2bf(tile[rb + 0][cc]);
        o.y = f2bf(tile[rb + 1][cc]);
        o.z = f2bf(tile[rb + 2][cc]);
        o.w = f2bf(tile[rb + 3][cc]);
        *(ushort4*)(d + (size_t)(c0 + cc) * R + r0 + rb) = o;
    }
}

// ---------------- fused 3-layer expert MLP: 4 experts x 64 rows per 16-wave WG ----------------
__global__ __launch_bounds__(1024, 1) void moe_fused(
    const float* __restrict__ x,            // [B][E][DIN]
    const float* __restrict__ b1,           // [E][H]
    const float* __restrict__ b2,           // [E][H]
    const float* __restrict__ b3,           // [E][DOUT]
    const unsigned short* __restrict__ W1t, // [E][H][DIN]  bf16
    const unsigned short* __restrict__ W2t, // [E][H][H]    bf16
    const unsigned short* __restrict__ W3t, // [E][DOUT][H] bf16
    float* __restrict__ out)                // [B][DOUT]  (pre-zeroed by prep)
{
    __shared__ unsigned short sMem[64 * NDIN + 2 * 64 * NH];  // 16KB X + 2x64KB H = 144KB
    unsigned short* sX  = sMem;
    unsigned short* sHA = sMem + 64 * NDIN;            // L1 output (read by L2)
    unsigned short* sHB = sHA + 64 * NH;               // L2 output (read by L3)

    const int tid  = threadIdx.x;
    const int wave = tid >> 6;            // 0..15
    const int lane = tid & 63;
    const int q    = lane >> 4;
    const int l16  = lane & 15;
    const int hi2  = l16 >> 2;
    const int lo2  = l16 & 3;
    const int qe   = (q ^ lo2) * 8;       // swizzled in-granule element offset

    // grid 512: xcd = lin&7; e-group = xcd>>1 (4 experts pinned per XCD pair);
    // row-tile = ((lin>>3)<<1)|(xcd&1) in 0..127.
    const int lin = blockIdx.x;
    const int xcd = lin & 7;
    const int eg  = xcd >> 1;
    const int rt  = ((lin >> 3) << 1) | (xcd & 1);
    const int b0  = rt << 6;
    const int nb  = wave * 32;            // 32 H-cols per wave in L1/L2

    // per-wave LDS A-frag base offsets (elements);  read addr = base + ((kt^hi2)<<5)
    int aH[4], aX[4];
#pragma unroll
    for (int m = 0; m < 4; ++m) {
        aH[m] = (m * 16 + l16) * NH   + qe;
        aX[m] = (m * 16 + l16) * NDIN + qe;
    }
    const int r0 = tid >> 4, c8 = (tid & 15) * 8;   // x staging coords (1024 thr = 64x16)

    // L3 wave mapping: (2 mp) x (4 n3) x (2 kh K-halves)
    const int n3 = wave & 3, mp = (wave >> 2) & 1, kh = wave >> 3;
    int a3[2];
#pragma unroll
    for (int i = 0; i < 2; ++i) a3[i] = ((2 * mp + i) * 16 + l16) * NH + qe;

    f32x4 oacc[2];
    oacc[0] = {0.f, 0.f, 0.f, 0.f}; oacc[1] = {0.f, 0.f, 0.f, 0.f};
    float bacc = 0.f;

    bf16x8 afr[4];      // A-frags, SINGLE-buffered (TLP covers latency)
    bf16x8 bfr[2][2];   // weight B-frags, 2-slot

    // ---- prologue: stage sX(e0): one bf16x8 per thread ----
    {
        const int e0 = eg * EG;
        const float* p = x + ((size_t)(b0 + r0) * NE + e0) * NDIN + c8;
        float4 u0 = *(const float4*)p, u1 = *(const float4*)(p + 4);
        *(bf16x8*)&sX[shx(r0, c8)] = cvt8(u0, u1);
    }
    __syncthreads();   // BAR-0: sX(e0) visible

#pragma unroll 1
    for (int ei = 0; ei < EG; ++ei) {
        const int e = eg * EG + ei;

        // W1 frags + b1 at iter top
        const unsigned short* wb1[2];
#pragma unroll
        for (int n = 0; n < 2; ++n)
            wb1[n] = W1t + (size_t)e * NH * NDIN + (size_t)(nb + n * 16 + l16) * NDIN + q * 8;
#pragma unroll
        for (int n = 0; n < 2; ++n)
            bfr[0][n] = *(const bf16x8*)(wb1[n]);
        float4 b1q[2];
#pragma unroll
        for (int n = 0; n < 2; ++n)
            b1q[n] = *(const float4*)(b1 + e * NH + nb + n * 16 + q * 4);

        // ---------------- layer 1: acc = X @ W1 + b1, 4 kt ----------------
        f32x4 acc[4][2];
#pragma unroll
        for (int n = 0; n < 2; ++n) {
            const f32x4 bi = {b1q[n].x, b1q[n].y, b1q[n].z, b1q[n].w};
#pragma unroll
            for (int m = 0; m < 4; ++m) acc[m][n] = bi;
        }

#pragma unroll
        for (int kt = 0; kt < 4; ++kt) {
            if (kt < 3)
#pragma unroll
                for (int n = 0; n < 2; ++n)
                    bfr[(kt + 1) & 1][n] = *(const bf16x8*)(wb1[n] + (kt + 1) * 32);
#pragma unroll
            for (int m = 0; m < 4; ++m)
                afr[m] = *(const bf16x8*)&sX[aX[m] + (((kt ^ hi2) & 3) << 5)];
#pragma unroll
            for (int m = 0; m < 4; ++m)
#pragma unroll
                for (int n = 0; n < 2; ++n)
                    acc[m][n] = __builtin_amdgcn_mfma_f32_16x16x32_bf16(
                        bfr[kt & 1][n], afr[m], acc[m][n], 0, 0, 0);
        }

        // W2 prologue + b2 in flight over the H1 epilogue + barrier
        const unsigned short* wb2[2];
#pragma unroll
        for (int n = 0; n < 2; ++n)
            wb2[n] = W2t + (size_t)e * NH * NH + (size_t)(nb + n * 16 + l16) * NH + q * 8;
#pragma unroll
        for (int n = 0; n < 2; ++n)
            bfr[0][n] = *(const bf16x8*)(wb2[n]);
        float4 b2q[2];
#pragma unroll
        for (int n = 0; n < 2; ++n)
            b2q[n] = *(const float4*)(b2 + e * NH + nb + n * 16 + q * 4);

        // H1 epilogue -> sHA (WAR-safe: L2(e-1) readers ended before BAR-2(e-1))
#pragma unroll
        for (int n = 0; n < 2; ++n) {
            const int c0 = nb + n * 16 + q * 4;
#pragma unroll
            for (int m = 0; m < 4; ++m) {
                bf16x4 pk;
#pragma unroll
                for (int r = 0; r < 4; ++r) pk[r] = (__bf16)fmaxf(acc[m][n][r], 0.f);
                *(bf16x4*)&sHA[shidx(m * 16 + l16, c0)] = pk;
            }
        }
        __syncthreads();   // BAR-1: sHA visible (also orders L3(e-1) before H2epi below)

        // ---------------- layer 2: acc2 = H1 @ W2 (+b2), 16 kt ----------------
        f32x4 acc2[4][2];
#pragma unroll
        for (int n = 0; n < 2; ++n) {
            const f32x4 bi = {b2q[n].x, b2q[n].y, b2q[n].z, b2q[n].w};
#pragma unroll
            for (int m = 0; m < 4; ++m) acc2[m][n] = bi;
        }

#pragma unroll
        for (int kt = 0; kt < 16; ++kt) {
            if (kt < 15)
#pragma unroll
                for (int n = 0; n < 2; ++n)
                    bfr[(kt + 1) & 1][n] = *(const bf16x8*)(wb2[n] + (kt + 1) * 32);
#pragma unroll
            for (int m = 0; m < 4; ++m)
                afr[m] = *(const bf16x8*)&sHA[aH[m] + (((kt ^ hi2)) << 5)];
#pragma unroll
            for (int m = 0; m < 4; ++m)
#pragma unroll
                for (int n = 0; n < 2; ++n)
                    acc2[m][n] = __builtin_amdgcn_mfma_f32_16x16x32_bf16(
                        bfr[kt & 1][n], afr[m], acc2[m][n], 0, 0, 0);
        }

        // W3 kh-half b3f preload (3 of 4 slots) + b3 + X(e+1) prefetch (8 regs)
        const unsigned short* wb3 = W3t + (size_t)e * NDO * NH + (size_t)(n3 * 16 + l16) * NH + q * 8;
        bf16x8 b3f[4];
#pragma unroll
        for (int j = 0; j < 3; ++j) b3f[j] = *(const bf16x8*)(wb3 + (kh * 8 + j) * 32);
        const float b3v = b3[e * NDO + n3 * 16 + l16];

        float4 xu0, xu1;
        {
            const int en = eg * EG + ((ei + 1) & (EG - 1));   // wrap: ei=3 redundant, harmless
            const float* p = x + ((size_t)(b0 + r0) * NE + en) * NDIN + c8;
            xu0 = *(const float4*)p; xu1 = *(const float4*)(p + 4);
        }

        // H2 epilogue -> sHB (WAR-safe: L3(e-1) readers ended before BAR-1(e))
#pragma unroll
        for (int n = 0; n < 2; ++n) {
            const int c0 = nb + n * 16 + q * 4;
#pragma unroll
            for (int m = 0; m < 4; ++m) {
                bf16x4 pk;
#pragma unroll
                for (int r = 0; r < 4; ++r) pk[r] = (__bf16)fmaxf(acc2[m][n][r], 0.f);
                *(bf16x4*)&sHB[shidx(m * 16 + l16, c0)] = pk;
            }
        }
        // stage sX(e+1) (WAR-safe: L1(e) readers ended before BAR-1(e))
        *(bf16x8*)&sX[shx(r0, c8)] = cvt8(xu0, xu1);
        __syncthreads();   // BAR-2: sHB + sX(e+1) visible

        // ---------------- layer 3: oacc += H2[kh-half] @ W3 ----------------
        bf16x8 a3f[2][2];
#pragma unroll
        for (int i = 0; i < 2; ++i)
            a3f[0][i] = *(const bf16x8*)&sHB[a3[i] + ((((kh * 8) ^ hi2)) << 5)];

#pragma unroll
        for (int j = 0; j < 8; ++j) {
            const int kt = kh * 8 + j;
            if (j < 7)
#pragma unroll
                for (int i = 0; i < 2; ++i)
                    a3f[(j + 1) & 1][i] = *(const bf16x8*)&sHB[a3[i] + ((((kt + 1) ^ hi2)) << 5)];
            if (j < 5)
                b3f[(j + 3) & 3] = *(const bf16x8*)(wb3 + (kh * 8 + j + 3) * 32);
#pragma unroll
            for (int i = 0; i < 2; ++i)
                oacc[i] = __builtin_amdgcn_mfma_f32_16x16x32_bf16(
                    a3f[j & 1][i], b3f[j & 3], oacc[i], 0, 0, 0);
        }
        bacc += kh ? 0.f : b3v;   // bias only from the kh=0 half (no double-count)
    }

    // final: 4-expert-accumulated contribution -> global fp32 atomics
#pragma unroll
    for (int i = 0; i < 2; ++i) {
        const int col = n3 * 16 + l16;
#pragma unroll
        for (int r = 0; r < 4; ++r) {
            const int row = b0 + (2 * mp + i) * 16 + q * 4 + r;
            unsafeAtomicAdd(out + (size_t)row * NDO + col, oacc[i][r] + bacc);
        }
    }
}

extern "C" void kernel_launch(void* const* d_in, const int* in_sizes, int n_in,
                              void* d_out, int out_size, void* d_ws, size_t ws_size,
                              hipStream_t stream) {
    const float* x  = (const float*)d_in[0];
    const float* W1 = (const float*)d_in[1];
    const float* b1 = (const float*)d_in[2];
    const float* W2 = (const float*)d_in[3];
    const float* b2 = (const float*)d_in[4];
    const float* W3 = (const float*)d_in[5];
    const float* b3 = (const float*)d_in[6];
    float* out = (float*)d_out;

    unsigned short* W1t = (unsigned short*)d_ws;            // [E][H][DIN]
    unsigned short* W2t = W1t + (size_t)NE * NH * NDIN;     // [E][H][H]
    unsigned short* W3t = W2t + (size_t)NE * NH * NH;       // [E][DOUT][H]

    prep_weights<<<dim3(88, NE), 256, 0, stream>>>(W1, W2, W3, W1t, W2t, W3t, out);
    moe_fused<<<dim3((NB / 64) * (NE / EG)), 1024, 0, stream>>>(x, b1, b2, b3, W1t, W2t, W3t, out);
}

// Round 10
// 204.970 us; speedup vs baseline: 1.4562x; 1.4426x over previous
//
#include <hip/hip_runtime.h>

// out[b,o] = sum_e ( relu(relu(x[b,e,:]@W1[e]+b1[e])@W2[e]+b2[e]) @ W3[e] + b3[e] )
// E=16, DIN=128, H=512, DOUT=64, B=8192.  94.5 GFLOP.
//
// R16 = R13 (best clean core, 203us) + FRAGMENT-PACKED weight layout.
// Diagnosis: R15 doubled occupancy (45%) -> dur unchanged => not TLP-bound.
// Residual un-modeled cost matches the weight-load gather: each bfr load
// touches 16 rows @1KB stride, 64B used/row -> up to 2x L2 sector
// amplification + 16-line scatter per instruction, a per-CU-bandwidth cost
// invariant to wave count (the session's signature).
// Fix: prep emits weights in EXACT fragment order:
//   W1f[e][wave][kt][n][lane][8], W2f same (NKT=16), W3f[e][n3][kt][lane][8].
//   Wave's per-kt load = contiguous 4KB burst (base + kt*2048 + n*512 + lane*8),
//   every sector fully used. Same bytes, same math -> absmax must stay EXACTLY
//   0.0078125 (correctness canary). Only addresses changed vs R13.
// R13 kept verbatim: dual-sH 2-barrier skeleton, EG=4 (atomics /4), rotating
//   b3f[8], X(e+1) 16-reg prefetch, swapped-operand b64 epilogue, bias-in-acc,
//   XCD expert pinning, launch_bounds(512,2), folded memset, no setprio.

#define NE   16
#define NDIN 128
#define NH   512
#define NDO  64
#define NB   8192
#define EG   4

using bf16x8 = __attribute__((ext_vector_type(8))) __bf16;
using bf16x4 = __attribute__((ext_vector_type(4))) __bf16;
using f32x4  = __attribute__((ext_vector_type(4))) float;

__device__ __forceinline__ unsigned short f2bf(float f) {
    union { float f; unsigned u; } v; v.f = f;
    unsigned r = v.u + 0x7FFFu + ((v.u >> 16) & 1u);   // RNE
    return (unsigned short)(r >> 16);
}

// compiler-fusable bf16 conversion (emits v_cvt_pk_bf16_f32 pairs)
__device__ __forceinline__ bf16x8 cvt8(float4 a, float4 b) {
    bf16x8 r;
    r[0] = (__bf16)a.x; r[1] = (__bf16)a.y; r[2] = (__bf16)a.z; r[3] = (__bf16)a.w;
    r[4] = (__bf16)b.x; r[5] = (__bf16)b.y; r[6] = (__bf16)b.z; r[7] = (__bf16)b.w;
    return r;
}

// Swizzled index (ushort units): 16B granules XOR'd by row&15 (0 conflicts measured).
__device__ __forceinline__ int shidx(int m, int n) {          // H tile, stride 512
    return m * NH + (((n >> 3) ^ (m & 15)) << 3) + (n & 7);
}
__device__ __forceinline__ int shx(int m, int n) {            // X tile, stride 128
    return m * NDIN + ((((n >> 3) ^ (m & 15)) & 15) << 3) + (n & 7);
}

// ---------------- prep: fp32 weights -> bf16 FRAGMENT-PACKED (+ out zeroing) ----------------
// value(e,t,kt,lane=q*16+l16,j) = Wsrc[e][kt*32 + q*8 + j][t*16 + l16]
// W1/W2 chunk offset: (((e*8 + t>>2)*NKT + kt)*4 + (t&3))*512 + lane*8   (t = wave*4+n)
// W3   chunk offset: ((e*4 + t)*16 + kt)*512 + lane*8                    (t = n3)
__global__ __launch_bounds__(256) void prep_weights(
    const float* __restrict__ W1, const float* __restrict__ W2, const float* __restrict__ W3,
    unsigned short* __restrict__ W1f, unsigned short* __restrict__ W2f, unsigned short* __restrict__ W3f,
    float* __restrict__ out)
{
    __shared__ float lds[32][521];   // 521 pad -> 2-way max on frag gather (free)
    const int job = blockIdx.x, tt = threadIdx.x;
    // fold the output memset: first 64 jobs clear 32KB each (2MB total)
    if (job < 64) {
        float4* oz = (float4*)(out + (size_t)job * 8192);
        const float4 z = {0.f, 0.f, 0.f, 0.f};
#pragma unroll
        for (int i = 0; i < 8; ++i) oz[i * 256 + tt] = z;
    }
    const float* src; unsigned short* dst; int e, kt, C, NKT, isW3;
    if (job < 64)       { e = job >> 2;                kt = job & 3;  src = W1; dst = W1f; C = NH;  NKT = 4;  isW3 = 0; }
    else if (job < 320) { int q = job - 64;  e = q >> 4; kt = q & 15; src = W2; dst = W2f; C = NH;  NKT = 16; isW3 = 0; }
    else                { int q = job - 320; e = q >> 4; kt = q & 15; src = W3; dst = W3f; C = NDO; NKT = 16; isW3 = 1; }

    // stage the 32 x C slab (k-rows kt*32..+31 of src[e])
    const float* s = src + ((size_t)e * (NKT * 32) + kt * 32) * C;
    const int nf4 = (32 * C) >> 2;
    for (int i = tt; i < nf4; i += 256) {
        const int r = i / (C >> 2), c4 = (i % (C >> 2)) * 4;
        const float4 v = *(const float4*)(s + (size_t)r * C + c4);
        lds[r][c4 + 0] = v.x; lds[r][c4 + 1] = v.y;
        lds[r][c4 + 2] = v.z; lds[r][c4 + 3] = v.w;
    }
    __syncthreads();

    // emit 1KB fragment chunks, coalesced (consecutive lanes -> consecutive 16B)
    const int npair = (C >> 4) * 64;
    for (int p = tt; p < npair; p += 256) {
        const int t = p >> 6, lane = p & 63, q = lane >> 4, l16 = lane & 15;
        union { unsigned short u[8]; uint4 v; } pk;
#pragma unroll
        for (int j = 0; j < 8; ++j) pk.u[j] = f2bf(lds[q * 8 + j][t * 16 + l16]);
        size_t off;
        if (isW3) off = (((size_t)e * 4 + t) * 16 + kt) * 512 + lane * 8;
        else      off = ((((size_t)e * 8 + (t >> 2)) * NKT + kt) * 4 + (t & 3)) * 512 + lane * 8;
        *(uint4*)(dst + off) = pk.v;
    }
}

// ---------------- fused 3-layer expert MLP: 4 experts x 64 rows per WG ----------------
__global__ __launch_bounds__(512, 2) void moe_fused(
    const float* __restrict__ x,            // [B][E][DIN]
    const float* __restrict__ b1,           // [E][H]
    const float* __restrict__ b2,           // [E][H]
    const float* __restrict__ b3,           // [E][DOUT]
    const unsigned short* __restrict__ W1f, // fragment-packed
    const unsigned short* __restrict__ W2f,
    const unsigned short* __restrict__ W3f,
    float* __restrict__ out)                // [B][DOUT]  (pre-zeroed by prep)
{
    __shared__ unsigned short sMem[64 * NDIN + 2 * 64 * NH];  // 16KB X + 2x64KB H = 144KB
    unsigned short* sX  = sMem;
    unsigned short* sHA = sMem + 64 * NDIN;            // L1 output (read by L2)
    unsigned short* sHB = sHA + 64 * NH;               // L2 output (read by L3)

    const int tid  = threadIdx.x;
    const int wave = tid >> 6;
    const int lane = tid & 63;
    const int q    = lane >> 4;
    const int l16  = lane & 15;
    const int hi2  = l16 >> 2;
    const int lo2  = l16 & 3;
    const int qe   = (q ^ lo2) * 8;       // swizzled in-granule element offset

    // grid 512: xcd = lin&7; e-group = xcd>>1 (4 experts pinned per XCD pair);
    // row-tile = ((lin>>3)<<1)|(xcd&1) in 0..127.
    const int lin = blockIdx.x;
    const int xcd = lin & 7;
    const int eg  = xcd >> 1;
    const int rt  = ((lin >> 3) << 1) | (xcd & 1);
    const int b0  = rt << 6;

    // per-wave LDS A-frag base offsets (elements);  read addr = base + ((kt^hi2)<<5)
    int aH[4], aX[4];
#pragma unroll
    for (int m = 0; m < 4; ++m) {
        aH[m] = (m * 16 + l16) * NH   + qe;
        aX[m] = (m * 16 + l16) * NDIN + qe;
    }
    const int r0 = tid >> 4, c8 = (tid & 15) * 8;   // x staging coords

    // L3 wave mapping (constant across experts)
    const int n3 = wave & 3, mp = wave >> 2;
    int a3[2];
#pragma unroll
    for (int i = 0; i < 2; ++i) a3[i] = ((2 * mp + i) * 16 + l16) * NH + qe;

    bf16x8 bfr[3][4], afr[3][4];

    f32x4 oacc[2];
    oacc[0] = {0.f, 0.f, 0.f, 0.f}; oacc[1] = {0.f, 0.f, 0.f, 0.f};
    float bacc = 0.f;

    // ---- prologue: stage sX(e0) ----
    {
        const int e0 = eg * EG;
        const float* p0 = x + ((size_t)(b0 + r0)      * NE + e0) * NDIN + c8;
        const float* p1 = x + ((size_t)(b0 + 32 + r0) * NE + e0) * NDIN + c8;
        float4 u0 = *(const float4*)p0, u1 = *(const float4*)(p0 + 4);
        float4 u2 = *(const float4*)p1, u3 = *(const float4*)(p1 + 4);
        *(bf16x8*)&sX[shx(r0, c8)]      = cvt8(u0, u1);
        *(bf16x8*)&sX[shx(32 + r0, c8)] = cvt8(u2, u3);
    }
    __syncthreads();   // BAR-0: sX(e0) visible

#pragma unroll 1
    for (int ei = 0; ei < EG; ++ei) {
        const int e = eg * EG + ei;

        // fragment-packed weight bases (contiguous 4KB per kt across n)
        const unsigned short* b1p = W1f + (size_t)e * NH * NDIN + wave * 8192  + lane * 8;
        const unsigned short* b2p = W2f + (size_t)e * NH * NH   + wave * 32768 + lane * 8;

        // W1 frags + b1 at iter top (L2-resident, amortized over 3 GEMMs)
#pragma unroll
        for (int s = 0; s < 2; ++s)
#pragma unroll
            for (int n = 0; n < 4; ++n)
                bfr[s][n] = *(const bf16x8*)(b1p + s * 2048 + n * 512);
        float4 b1q[4];
#pragma unroll
        for (int n = 0; n < 4; ++n)
            b1q[n] = *(const float4*)(b1 + e * NH + wave * 64 + n * 16 + q * 4);

        // ---------------- layer 1: acc = X @ W1 + b1, 4 kt ----------------
        f32x4 acc[4][4];
#pragma unroll
        for (int n = 0; n < 4; ++n) {
            const f32x4 bi = {b1q[n].x, b1q[n].y, b1q[n].z, b1q[n].w};
#pragma unroll
            for (int m = 0; m < 4; ++m) acc[m][n] = bi;
        }
#pragma unroll
        for (int s = 0; s < 2; ++s)
#pragma unroll
            for (int m = 0; m < 4; ++m)
                afr[s][m] = *(const bf16x8*)&sX[aX[m] + (((s ^ hi2) & 3) << 5)];

#pragma unroll
        for (int kt = 0; kt < 4; ++kt) {
            const int cur = kt % 3, pre = (kt + 2) % 3;
            if (kt < 2) {
#pragma unroll
                for (int n = 0; n < 4; ++n)
                    bfr[pre][n] = *(const bf16x8*)(b1p + (kt + 2) * 2048 + n * 512);
#pragma unroll
                for (int m = 0; m < 4; ++m)
                    afr[pre][m] = *(const bf16x8*)&sX[aX[m] + ((((kt + 2) ^ hi2) & 3) << 5)];
            }
#pragma unroll
            for (int m = 0; m < 4; ++m)
#pragma unroll
                for (int n = 0; n < 4; ++n)
                    acc[m][n] = __builtin_amdgcn_mfma_f32_16x16x32_bf16(
                        bfr[cur][n], afr[cur][m], acc[m][n], 0, 0, 0);
        }

        // W2 prologue + b2 in flight over the H1 epilogue + barrier
#pragma unroll
        for (int s = 0; s < 2; ++s)
#pragma unroll
            for (int n = 0; n < 4; ++n)
                bfr[s][n] = *(const bf16x8*)(b2p + s * 2048 + n * 512);
        float4 b2q[4];
#pragma unroll
        for (int n = 0; n < 4; ++n)
            b2q[n] = *(const float4*)(b2 + e * NH + wave * 64 + n * 16 + q * 4);

        // H1 epilogue -> sHA (WAR-safe: L2(e-1) readers ended before BAR-2(e-1))
#pragma unroll
        for (int n = 0; n < 4; ++n) {
            const int c0 = wave * 64 + n * 16 + q * 4;
#pragma unroll
            for (int m = 0; m < 4; ++m) {
                bf16x4 pk;
#pragma unroll
                for (int r = 0; r < 4; ++r) pk[r] = (__bf16)fmaxf(acc[m][n][r], 0.f);
                *(bf16x4*)&sHA[shidx(m * 16 + l16, c0)] = pk;
            }
        }
        __syncthreads();   // BAR-1: sHA visible (also orders L3(e-1) before H2epi below)

        // ---------------- layer 2: acc2 = H1 @ W2 (+b2), 16 kt ----------------
        f32x4 acc2[4][4];
#pragma unroll
        for (int n = 0; n < 4; ++n) {
            const f32x4 bi = {b2q[n].x, b2q[n].y, b2q[n].z, b2q[n].w};
#pragma unroll
            for (int m = 0; m < 4; ++m) acc2[m][n] = bi;
        }
#pragma unroll
        for (int s = 0; s < 2; ++s)
#pragma unroll
            for (int m = 0; m < 4; ++m)
                afr[s][m] = *(const bf16x8*)&sHA[aH[m] + (((s ^ hi2)) << 5)];

#pragma unroll
        for (int kt = 0; kt < 16; ++kt) {
            const int cur = kt % 3, pre = (kt + 2) % 3;
            if (kt < 14) {
#pragma unroll
                for (int n = 0; n < 4; ++n)
                    bfr[pre][n] = *(const bf16x8*)(b2p + (kt + 2) * 2048 + n * 512);
#pragma unroll
                for (int m = 0; m < 4; ++m)
                    afr[pre][m] = *(const bf16x8*)&sHA[aH[m] + ((((kt + 2) ^ hi2)) << 5)];
            }
#pragma unroll
            for (int m = 0; m < 4; ++m)
#pragma unroll
                for (int n = 0; n < 4; ++n)
                    acc2[m][n] = __builtin_amdgcn_mfma_f32_16x16x32_bf16(
                        bfr[cur][n], afr[cur][m], acc2[m][n], 0, 0, 0);
        }

        // W3 first half + b3; X(e+1) -> regs (16 VGPR, held across one epilogue)
        const unsigned short* b3p = W3f + (size_t)e * NDO * NH + n3 * 8192 + lane * 8;
        bf16x8 b3f[8];
#pragma unroll
        for (int j = 0; j < 8; ++j) b3f[j] = *(const bf16x8*)(b3p + j * 512);
        const float b3v = b3[e * NDO + n3 * 16 + l16];

        float4 xu0, xu1, xu2, xu3;
        {
            const int en = eg * EG + ((ei + 1) & (EG - 1));   // wrap: ei=3 redundant, harmless
            const float* pn0 = x + ((size_t)(b0 + r0)      * NE + en) * NDIN + c8;
            const float* pn1 = x + ((size_t)(b0 + 32 + r0) * NE + en) * NDIN + c8;
            xu0 = *(const float4*)pn0; xu1 = *(const float4*)(pn0 + 4);
            xu2 = *(const float4*)pn1; xu3 = *(const float4*)(pn1 + 4);
        }

        // H2 epilogue -> sHB (WAR-safe: L3(e-1) readers ended before BAR-1(e))
#pragma unroll
        for (int n = 0; n < 4; ++n) {
            const int c0 = wave * 64 + n * 16 + q * 4;
#pragma unroll
            for (int m = 0; m < 4; ++m) {
                bf16x4 pk;
#pragma unroll
                for (int r = 0; r < 4; ++r) pk[r] = (__bf16)fmaxf(acc2[m][n][r], 0.f);
                *(bf16x4*)&sHB[shidx(m * 16 + l16, c0)] = pk;
            }
        }
        // stage sX(e+1) (WAR-safe: L1(e) readers ended before BAR-1(e))
        *(bf16x8*)&sX[shx(r0, c8)]      = cvt8(xu0, xu1);
        *(bf16x8*)&sX[shx(32 + r0, c8)] = cvt8(xu2, xu3);
        __syncthreads();   // BAR-2: sHB + sX(e+1) visible

        // ---------------- layer 3: oacc += H2 @ W3 (b3f[8] rotating; A lookahead-3) ----------------
        bf16x8 a3f[4][2];
#pragma unroll
        for (int s = 0; s < 3; ++s)
#pragma unroll
            for (int i = 0; i < 2; ++i)
                a3f[s][i] = *(const bf16x8*)&sHB[a3[i] + (((s ^ hi2)) << 5)];

#pragma unroll
        for (int kt = 0; kt < 16; ++kt) {
            const int cur = kt & 3;
            if (kt < 13) {
                const int pre = (kt + 3) & 3;
#pragma unroll
                for (int i = 0; i < 2; ++i)
                    a3f[pre][i] = *(const bf16x8*)&sHB[a3[i] + ((((kt + 3) ^ hi2)) << 5)];
            }
#pragma unroll
            for (int i = 0; i < 2; ++i)
                oacc[i] = __builtin_amdgcn_mfma_f32_16x16x32_bf16(
                    a3f[cur][i], b3f[kt & 7], oacc[i], 0, 0, 0);
            if (kt < 8)    // rotate: slot kt&7 dead after its MFMA; load frag kt+8
                b3f[kt & 7] = *(const bf16x8*)(b3p + (kt + 8) * 512);
        }
        bacc += b3v;
    }

    // final: 4-expert-accumulated contribution -> global fp32 atomics (1 set per block)
#pragma unroll
    for (int i = 0; i < 2; ++i) {
        const int col = n3 * 16 + l16;
#pragma unroll
        for (int r = 0; r < 4; ++r) {
            const int row = b0 + (2 * mp + i) * 16 + q * 4 + r;
            unsafeAtomicAdd(out + (size_t)row * NDO + col, oacc[i][r] + bacc);
        }
    }
}

extern "C" void kernel_launch(void* const* d_in, const int* in_sizes, int n_in,
                              void* d_out, int out_size, void* d_ws, size_t ws_size,
                              hipStream_t stream) {
    const float* x  = (const float*)d_in[0];
    const float* W1 = (const float*)d_in[1];
    const float* b1 = (const float*)d_in[2];
    const float* W2 = (const float*)d_in[3];
    const float* b2 = (const float*)d_in[4];
    const float* W3 = (const float*)d_in[5];
    const float* b3 = (const float*)d_in[6];
    float* out = (float*)d_out;

    unsigned short* W1f = (unsigned short*)d_ws;            // [E*8][4][4][64][8]
    unsigned short* W2f = W1f + (size_t)NE * NH * NDIN;     // [E*8][16][4][64][8]
    unsigned short* W3f = W2f + (size_t)NE * NH * NH;       // [E*4][16][64][8]

    prep_weights<<<dim3(576), 256, 0, stream>>>(W1, W2, W3, W1f, W2f, W3f, out);
    moe_fused<<<dim3((NB / 64) * (NE / EG)), 512, 0, stream>>>(x, b1, b2, b3, W1f, W2f, W3f, out);
}